// Round 5
// baseline (7008.043 us; speedup 1.0000x reference)
//
#include <hip/hip_runtime.h>
#include <cstdint>

#define BB 256
#define TT 4096
#define FDIM 16
#define HH 128

typedef unsigned long long u64;
typedef float f32x2 __attribute__((ext_vector_type(2)));
typedef uint32_t u32x4 __attribute__((ext_vector_type(4)));

// ---------------------------------------------------------------------------
// asm helpers. All vm loads/stores are asm volatile => issue order == source
// order, so s_waitcnt vmcnt(N) ledgers are exact. After every wait:
// sched_barrier(0) (rule #18).
// ---------------------------------------------------------------------------
__device__ __forceinline__ uint32_t lds_addr32(const void* p) {
  return (uint32_t)(uintptr_t)p;
}
__device__ __forceinline__ f32x2 glb_load_b64(uint32_t voff, const void* base) {
  f32x2 d;
  asm volatile("global_load_dwordx2 %0, %1, %2" : "=v"(d) : "v"(voff), "s"(base));
  return d;
}
__device__ __forceinline__ uint32_t glb_load_b32(uint32_t voff, const void* base) {
  uint32_t d;
  asm volatile("global_load_dword %0, %1, %2" : "=v"(d) : "v"(voff), "s"(base));
  return d;
}
__device__ __forceinline__ u32x4 glb_load_b128(uint32_t voff, const void* base) {
  u32x4 d;
  asm volatile("global_load_dwordx4 %0, %1, %2" : "=v"(d) : "v"(voff), "s"(base));
  return d;
}
__device__ __forceinline__ void glb_store_b64(uint32_t voff, f32x2 v, void* base) {
  asm volatile("global_store_dwordx2 %0, %1, %2" :: "v"(voff), "v"(v), "s"(base));
}
#define WAIT_VM(N)                                           \
  {                                                          \
    asm volatile("s_waitcnt vmcnt(" #N ")" ::: "memory");    \
    __builtin_amdgcn_sched_barrier(0);                       \
  }
#define WAIT_LGKM(N)                                         \
  {                                                          \
    asm volatile("s_waitcnt lgkmcnt(" #N ")" ::: "memory");  \
    __builtin_amdgcn_sched_barrier(0);                       \
  }
#define DS_READ_OFF(D, A, OFF) \
  asm volatile("ds_read_b32 %0, %1 offset:" #OFF : "=v"(D) : "v"(A));

// Packed fp32 add (two independent IEEE-rn adds; dataflow pins association).
__device__ __forceinline__ f32x2 pk_add(f32x2 a, f32x2 b) {
  f32x2 d;
  asm("v_pk_add_f32 %0, %1, %2" : "=v"(d) : "v"(a), "v"(b));
  return d;
}

__device__ __forceinline__ u64 rfl64(u64 x) {
  uint32_t lo = (uint32_t)__builtin_amdgcn_readfirstlane((int)(uint32_t)x);
  uint32_t hi = (uint32_t)__builtin_amdgcn_readfirstlane((int)(uint32_t)(x >> 32));
  return ((u64)hi << 32) | lo;
}

// 64-lane DPP sum; result valid in lane 63 (same op sequence as rounds 1-4).
__device__ __forceinline__ float wave_red_add63(float v) {
#define DPP_ADD(c)                                                             \
  v += __int_as_float(                                                         \
      __builtin_amdgcn_update_dpp(0, __float_as_int(v), c, 0xF, 0xF, true))
  DPP_ADD(0x111);
  DPP_ADD(0x112);
  DPP_ADD(0x114);
  DPP_ADD(0x118);
  DPP_ADD(0x142);
  DPP_ADD(0x143);
#undef DPP_ADD
  return v;
}
__device__ __forceinline__ float bcast63(float v) {
  return __int_as_float(__builtin_amdgcn_readlane(__float_as_int(v), 63));
}

// ---------------------------------------------------------------------------
// Kernel 0: transposed weight copies in workspace.
// w1t: 49 rows of 512B; row j<32 = (W1[l][j], W1[64+l][j]); rows 32..48 zero
//      (guard-bit sentinels for branchless 16-slot extraction).
// w2t: 129 rows; row j<128 real, row 128 zero (sentinel).
// ---------------------------------------------------------------------------
__global__ __launch_bounds__(64) void snn_prep(const float* __restrict__ W1,
                                               const float* __restrict__ W2,
                                               f32x2* __restrict__ w1t,
                                               f32x2* __restrict__ w2t) {
  const int l = threadIdx.x;
  for (int j = 0; j < 49; ++j)
    w1t[j * 64 + l] = (j < 32) ? f32x2{W1[l * 32 + j], W1[(64 + l) * 32 + j]}
                               : f32x2{0.f, 0.f};
  for (int j = 0; j < 129; ++j)
    w2t[j * 64 + l] = (j < 128) ? f32x2{W2[l * 128 + j], W2[(64 + l) * 128 + j]}
                                : f32x2{0.f, 0.f};
}

// ---------------------------------------------------------------------------
// Kernel 1: delta encode -> 32-bit masks (unchanged from passing round 4).
// ---------------------------------------------------------------------------
__global__ __launch_bounds__(64) void snn_encode(const float* __restrict__ x,
                                                 uint32_t* __restrict__ masks) {
  __shared__ float tile[2][4][64][16];  // 32 KiB
  const int lane = threadIdx.x;
  const int sub = lane >> 4;
  const int f = lane & 15;
  const int b0 = blockIdx.x * 4;
  float ref = x[(size_t)(b0 + sub) * (TT * FDIM) + f];

  const float4* xv = (const float4*)x;
  float4 ld[16];
#define K1_ISSUE(G)                                                           \
  _Pragma("unroll") for (int k = 0; k < 16; ++k) {                            \
    int idx4 = k * 64 + lane;                                                 \
    int bl = idx4 >> 8;                                                       \
    int r = idx4 & 255;                                                       \
    ld[k] = xv[(size_t)(b0 + bl) * (TT * 4) + (size_t)(G) * 256 + r];         \
  }
#define K1_WRITE(BUF)                                                         \
  _Pragma("unroll") for (int k = 0; k < 16; ++k) {                            \
    int idx4 = k * 64 + lane;                                                 \
    int bl = idx4 >> 8;                                                       \
    int r = idx4 & 255;                                                       \
    ((float4*)&tile[BUF][bl][0][0])[r] = ld[k];                               \
  }
#define CHUNK_ISSUE(ARR, A)                                                   \
  {                                                                           \
    DS_READ_OFF(ARR[0], A, 0);                                                \
    DS_READ_OFF(ARR[1], A, 64);                                               \
    DS_READ_OFF(ARR[2], A, 128);                                              \
    DS_READ_OFF(ARR[3], A, 192);                                              \
    DS_READ_OFF(ARR[4], A, 256);                                              \
    DS_READ_OFF(ARR[5], A, 320);                                              \
    DS_READ_OFF(ARR[6], A, 384);                                              \
    DS_READ_OFF(ARR[7], A, 448);                                              \
  }
#define PROC8(ARR, TBASE)                                                     \
  _Pragma("unroll") for (int i = 0; i < 8; ++i) {                             \
    float cur = ARR[i];                                                       \
    float diff = cur - ref;                                                   \
    bool onb = diff >= 0.5f;                                                  \
    bool offb = diff <= -0.5f;                                                \
    u64 bon = __ballot(onb);                                                  \
    u64 boff = __ballot(offb);                                                \
    ref = (onb || offb) ? cur : ref;                                          \
    if (f == 0) {                                                             \
      uint32_t mk = (uint32_t)((bon >> (sub * 16)) & 0xFFFFull) |             \
                    ((uint32_t)((boff >> (sub * 16)) & 0xFFFFull) << 16);     \
      masks[(size_t)(b0 + sub) * TT + ((TBASE) + i)] = mk;                    \
    }                                                                         \
  }

  const uint32_t tbase =
      lds_addr32(&tile[0][0][0][0]) + (uint32_t)sub * 4096u + (uint32_t)f * 4u;

  K1_ISSUE(0);
  K1_WRITE(0);
  WAIT_LGKM(0);
  for (int g = 0; g < TT / 64; ++g) {
    if (g + 1 < TT / 64) K1_ISSUE(g + 1);
    const int buf = g & 1;
    const uint32_t caddr = tbase + (uint32_t)buf * 16384u;
    float va[8], vb[8];
    CHUNK_ISSUE(va, caddr);
#pragma unroll
    for (int c = 0; c < 8; ++c) {
      if (c < 7) {
        uint32_t an = caddr + (uint32_t)(c + 1) * 512u;
        if (c & 1) {
          CHUNK_ISSUE(va, an);
        } else {
          CHUNK_ISSUE(vb, an);
        }
        WAIT_LGKM(8);
      } else {
        WAIT_LGKM(0);
      }
      if (c & 1) {
        PROC8(vb, g * 64 + c * 8);
      } else {
        PROC8(va, g * 64 + c * 8);
      }
    }
    if (g + 1 < TT / 64) {
      K1_WRITE((g + 1) & 1);
      WAIT_LGKM(0);
    }
  }
#undef PROC8
#undef CHUNK_ISSUE
#undef K1_WRITE
#undef K1_ISSUE
}

// ---------------------------------------------------------------------------
// Kernel 2: two-phase SNN core, one wave per batch (256 blocks).
// Phase 1: m1-scan. W1 slot loads (vm) pipelined 3 steps ahead, constant
//   WAIT_VM(34)/step; spikes (u64 x2) written to 64KB LDS.
// Phase 2: m2-scan + L3. W2 slot loads (vm) pipelined 2 steps ahead,
//   constant WAIT_VM(33)/step; only the ~12cy m2 update is loop-carried.
// All accumulation orders identical to the passing round-4 kernel.
// ---------------------------------------------------------------------------
__global__ __launch_bounds__(64, 1) void snn_fused(
    const uint32_t* __restrict__ masks, const f32x2* __restrict__ w1t,
    const f32x2* __restrict__ w2t, const float* __restrict__ b1,
    const float* __restrict__ b2, const float* __restrict__ W3,
    const float* __restrict__ b3, float* __restrict__ out) {
  __shared__ u64 spkL[TT][2];  // 64 KiB spike ballots
  const int lane = threadIdx.x;
  const int b = blockIdx.x;
  const uint32_t lane8 = (uint32_t)lane * 8u;

  const f32x2 bias1 = {b1[lane], b1[64 + lane]};
  const f32x2 bias2 = {b2[lane], b2[64 + lane]};
  const float w30a = W3[lane], w30b = W3[64 + lane];
  const float w31a = W3[128 + lane], w31b = W3[192 + lane];
  const float b30 = b3[0], b31 = b3[1];
  const uint32_t* mrow = masks + (size_t)b * TT;

  float m1a = 0.f, m1b = 0.f, m2a = 0.f, m2b = 0.f, m3x = 0.f, m3y = 0.f;

  // ================= PHASE 1: m1 scan, spikes -> LDS =================
  // Guard-bit extraction: 16 guard bits at 32..47 -> slot j in [0,48),
  // rows 32..48 of w1t are zeros. 3 SALU/slot, no branches, exact order.
#define P1ISSUE(BUF, MK)                                                      \
  {                                                                           \
    u64 mm_ = (u64)(MK) | 0xFFFF00000000ull;                                  \
    _Pragma("unroll") for (int k = 0; k < 16; ++k) {                          \
      uint32_t j_ = (uint32_t)__builtin_ctzll(mm_);                           \
      mm_ &= mm_ - 1;                                                         \
      BUF[k] = glb_load_b64((j_ << 9) + lane8, w1t);                          \
    }                                                                         \
  }
  // vm ledger/step: 16 slot loads + 1 mask dword. At consume(t), ops newer
  // than [slots(t), mld(t+3)] = 16+1+16+1 = 34 -> WAIT_VM(34) retires both.
#define P1STEP(BUF_CUR, BUF_ISS, VML_USE, VML_ISS, T)                         \
  {                                                                           \
    WAIT_VM(34);                                                              \
    f32x2 c1 = {0.f, 0.f};                                                    \
    _Pragma("unroll") for (int k = 0; k < 16; ++k) c1 = pk_add(c1, BUF_CUR[k]); \
    c1 = pk_add(c1, bias1);                                                   \
    float n0 = __fadd_rn(__fmul_rn(0.9f, m1a), c1.x);                         \
    float n1 = __fadd_rn(__fmul_rn(0.9f, m1b), c1.y);                         \
    m1a = (m1a > 1.f) ? (n0 - 1.f) : n0;                                      \
    m1b = (m1b > 1.f) ? (n1 - 1.f) : n1;                                      \
    u64 s0_ = __ballot(m1a > 1.f);                                            \
    u64 s1_ = __ballot(m1b > 1.f);                                            \
    if (lane == 0) {                                                          \
      spkL[(T) & (TT - 1)][0] = s0_;                                          \
      spkL[(T) & (TT - 1)][1] = s1_;                                          \
    }                                                                         \
    uint32_t mk_ = (uint32_t)__builtin_amdgcn_readfirstlane((int)(VML_USE));  \
    P1ISSUE(BUF_ISS, mk_);                                                    \
    VML_ISS = glb_load_b32((uint32_t)(((T + 6) & (TT - 1)) * 4), mrow);       \
  }

  {
    f32x2 A0[16], A1[16], A2[16], A3[16];
    uint32_t vml0, vml1, vml2, vml3;
    u32x4 mb = glb_load_b128(0u, mrow);
    WAIT_VM(0);
    uint32_t mk0 = (uint32_t)__builtin_amdgcn_readfirstlane((int)mb.x);
    uint32_t mk1 = (uint32_t)__builtin_amdgcn_readfirstlane((int)mb.y);
    uint32_t mk2 = (uint32_t)__builtin_amdgcn_readfirstlane((int)mb.z);
    P1ISSUE(A0, mk0);
    vml3 = glb_load_b32(3u * 4u, mrow);
    P1ISSUE(A1, mk1);
    vml0 = glb_load_b32(4u * 4u, mrow);
    P1ISSUE(A2, mk2);
    vml1 = glb_load_b32(5u * 4u, mrow);
    for (int t0 = 0; t0 < TT; t0 += 4) {
      P1STEP(A0, A3, vml3, vml2, t0 + 0);
      P1STEP(A1, A0, vml0, vml3, t0 + 1);
      P1STEP(A2, A1, vml1, vml0, t0 + 2);
      P1STEP(A3, A2, vml2, vml1, t0 + 3);
    }
    WAIT_VM(0);  // drain overhang (slots 4096..4098, mlds)
  }
#undef P1STEP
#undef P1ISSUE

  // ================= PHASE 2: m2 scan + L3 =================
#define EXTRACT(J)                                                            \
  {                                                                           \
    bool av_ = (a_ != 0);                                                     \
    bool bv_ = (b_ != 0);                                                     \
    uint32_t ja_ = av_ ? (uint32_t)__builtin_ctzll(a_) : 0u;                  \
    uint32_t jb_ = bv_ ? 64u + (uint32_t)__builtin_ctzll(b_) : 128u;          \
    J = av_ ? ja_ : jb_;                                                      \
    u64 an_ = a_ & (a_ - 1);                                                  \
    u64 bn_ = b_ & (b_ - 1);                                                  \
    b_ = (!av_ && bv_) ? bn_ : b_;                                            \
    a_ = av_ ? an_ : a_;                                                      \
  }
#define P2ISSUE(BUF, AIN, BIN, RA, RB)                                        \
  {                                                                           \
    u64 a_ = (AIN), b_ = (BIN);                                               \
    _Pragma("unroll") for (int k = 0; k < 32; ++k) {                          \
      uint32_t j_;                                                            \
      EXTRACT(j_);                                                            \
      BUF[k] = glb_load_b64((j_ << 9) + lane8, w2t);                          \
    }                                                                         \
    RA = a_;                                                                  \
    RB = b_;                                                                  \
  }
  // vm ledger/step: [32 slots][store]. Newer than slots(t) at consume =
  // st(t-1) + slots(t+1) = 33 -> WAIT_VM(33).
#define P2STEP(BUF, RA, RB, T)                                                \
  {                                                                           \
    u64 na_ = spkL[((T) + 2) & (TT - 1)][0]; /* LDS prefetch, above wall */   \
    u64 nb_ = spkL[((T) + 2) & (TT - 1)][1];                                  \
    WAIT_VM(33);                                                              \
    f32x2 c2 = {0.f, 0.f};                                                    \
    _Pragma("unroll") for (int k = 0; k < 32; ++k) c2 = pk_add(c2, BUF[k]);   \
    if (RA | RB) { /* rare >32-spike tail: exact order, drain path */         \
      u64 ta_ = RA;                                                           \
      while (ta_) {                                                           \
        uint32_t j_ = (uint32_t)__builtin_ctzll(ta_);                         \
        ta_ &= ta_ - 1;                                                       \
        f32x2 tw_ = glb_load_b64((j_ << 9) + lane8, w2t);                     \
        WAIT_VM(0);                                                           \
        c2 = pk_add(c2, tw_);                                                 \
      }                                                                       \
      u64 tb_ = RB;                                                           \
      while (tb_) {                                                           \
        uint32_t j_ = 64u + (uint32_t)__builtin_ctzll(tb_);                   \
        tb_ &= tb_ - 1;                                                       \
        f32x2 tw_ = glb_load_b64((j_ << 9) + lane8, w2t);                     \
        WAIT_VM(0);                                                           \
        c2 = pk_add(c2, tw_);                                                 \
      }                                                                       \
    }                                                                         \
    c2 = pk_add(c2, bias2);                                                   \
    float u0 = __fadd_rn(__fmul_rn(0.9f, m2a), c2.x);                         \
    float u1 = __fadd_rn(__fmul_rn(0.9f, m2b), c2.y);                         \
    m2a = (m2a > 1.f) ? (u0 - 1.f) : u0;                                      \
    m2b = (m2b > 1.f) ? (u1 - 1.f) : u1;                                      \
    bool q0 = m2a > 1.f;                                                      \
    bool q1 = m2b > 1.f;                                                      \
    float p0 = (q0 ? w30a : 0.f) + (q1 ? w30b : 0.f);                         \
    float p1 = (q0 ? w31a : 0.f) + (q1 ? w31b : 0.f);                         \
    float c3x = bcast63(wave_red_add63(p0)) + b30;                            \
    float c3y = bcast63(wave_red_add63(p1)) + b31;                            \
    float e0 = __fadd_rn(__fmul_rn(0.9f, m3x), c3x);                          \
    float e1 = __fadd_rn(__fmul_rn(0.9f, m3y), c3y);                          \
    m3x = (m3x > 1.f) ? (e0 - 1.f) : e0;                                      \
    m3y = (m3y > 1.f) ? (e1 - 1.f) : e1;                                      \
    P2ISSUE(BUF, rfl64(na_), rfl64(nb_), RA, RB); /* slots(t+2) */            \
    f32x2 o_ = {m3x, m3y};                                                    \
    glb_store_b64((uint32_t)((((size_t)(T)) * BB + b) * 8), o_, out);         \
  }

  {
    f32x2 B0[32], B1[32];
    u64 ra0, rb0, ra1, rb1;
    u64 k0a = spkL[0][0], k0b = spkL[0][1];
    u64 k1a = spkL[1][0], k1b = spkL[1][1];
    P2ISSUE(B0, rfl64(k0a), rfl64(k0b), ra0, rb0);
    {  // dummy store to w1t sentinel row 32 (zeros over zeros) - ledger prime
      f32x2 z_ = {0.f, 0.f};
      glb_store_b64(16384u + lane8, z_, (void*)w1t);
    }
    P2ISSUE(B1, rfl64(k1a), rfl64(k1b), ra1, rb1);
    for (int t0 = 0; t0 < TT; t0 += 2) {
      P2STEP(B0, ra0, rb0, t0 + 0);
      P2STEP(B1, ra1, rb1, t0 + 1);
    }
  }
#undef P2STEP
#undef P2ISSUE
#undef EXTRACT
}

extern "C" void kernel_launch(void* const* d_in, const int* in_sizes, int n_in,
                              void* d_out, int out_size, void* d_ws,
                              size_t ws_size, hipStream_t stream) {
  const float* x = (const float*)d_in[0];
  const float* W1 = (const float*)d_in[1];
  const float* b1 = (const float*)d_in[2];
  const float* W2 = (const float*)d_in[3];
  const float* b2 = (const float*)d_in[4];
  const float* W3 = (const float*)d_in[5];
  const float* b3 = (const float*)d_in[6];
  float* out = (float*)d_out;

  uint32_t* masks = (uint32_t*)d_ws;                              // 4 MiB
  char* wbase = (char*)d_ws + (size_t)BB * TT * 4;
  f32x2* w1t = (f32x2*)wbase;                                     // 25088 B
  f32x2* w2t = (f32x2*)(wbase + 32768);                           // 66048 B

  snn_prep<<<1, 64, 0, stream>>>(W1, W2, w1t, w2t);
  snn_encode<<<BB / 4, 64, 0, stream>>>(x, masks);
  snn_fused<<<BB, 64, 0, stream>>>(masks, w1t, w2t, b1, b2, W3, b3, out);
}

// Round 6
// 2378.493 us; speedup vs baseline: 2.9464x; 2.9464x over previous
//
#include <hip/hip_runtime.h>
#include <cstdint>

#define BB 256
#define TT 4096
#define FDIM 16
#define HH 128
#define CH 32           // timesteps per chunk
#define NCH (TT / CH)   // 128 chunks
#define NPROD 7         // producer waves; wave 7 = consumer
#define NTHR 512

typedef unsigned long long u64;
typedef float f32x2 __attribute__((ext_vector_type(2)));
typedef uint32_t u32x4 __attribute__((ext_vector_type(4)));

// ---------------------------------------------------------------------------
// asm helpers. All ledgered memory ops are asm volatile => issue order ==
// program order; counted s_waitcnt ledgers are exact. After every wait:
// sched_barrier(0) (skill rule #18).
// ---------------------------------------------------------------------------
__device__ __forceinline__ uint32_t lds_addr32(const void* p) {
  return (uint32_t)(uintptr_t)p;
}
__device__ __forceinline__ f32x2 glb_load_b64(uint32_t voff, const void* base) {
  f32x2 d;
  asm volatile("global_load_dwordx2 %0, %1, %2" : "=v"(d) : "v"(voff), "s"(base));
  return d;
}
__device__ __forceinline__ void ds_write_b128_at(uint32_t addr, u32x4 v) {
  asm volatile("ds_write_b128 %0, %1" ::"v"(addr), "v"(v));
}
#define WAIT_VM(N)                                          \
  {                                                         \
    asm volatile("s_waitcnt vmcnt(" #N ")" ::: "memory");   \
    __builtin_amdgcn_sched_barrier(0);                      \
  }
#define WAIT_LGKM(N)                                        \
  {                                                         \
    asm volatile("s_waitcnt lgkmcnt(" #N ")" ::: "memory"); \
    __builtin_amdgcn_sched_barrier(0);                      \
  }
#define DSR64(D, A, OFF) \
  asm volatile("ds_read_b64 %0, %1 offset:" #OFF : "=v"(D) : "v"(A));
#define DS_READ_OFF(D, A, OFF) \
  asm volatile("ds_read_b32 %0, %1 offset:" #OFF : "=v"(D) : "v"(A));

// Packed fp32 add (two independent IEEE-rn adds; dataflow pins association).
__device__ __forceinline__ f32x2 pk_add(f32x2 a, f32x2 b) {
  f32x2 d;
  asm("v_pk_add_f32 %0, %1, %2" : "=v"(d) : "v"(a), "v"(b));
  return d;
}
__device__ __forceinline__ u64 rfl64(u64 x) {
  uint32_t lo = (uint32_t)__builtin_amdgcn_readfirstlane((int)(uint32_t)x);
  uint32_t hi = (uint32_t)__builtin_amdgcn_readfirstlane((int)(uint32_t)(x >> 32));
  return ((u64)hi << 32) | lo;
}
// 64-lane DPP sum; result valid in lane 63 (same op sequence as rounds 1-5).
__device__ __forceinline__ float wave_red_add63(float v) {
#define DPP_ADD(c)                                                             \
  v += __int_as_float(                                                         \
      __builtin_amdgcn_update_dpp(0, __float_as_int(v), c, 0xF, 0xF, true))
  DPP_ADD(0x111);
  DPP_ADD(0x112);
  DPP_ADD(0x114);
  DPP_ADD(0x118);
  DPP_ADD(0x142);
  DPP_ADD(0x143);
#undef DPP_ADD
  return v;
}

// ---------------------------------------------------------------------------
// Kernel 0: transposed weights in workspace.
// w1t: 64 rows of 512B; rows 0..31 = (W1[l][j], W1[64+l][j]); 32..63 zero
//      (guard-bit sentinels for branchless 24-slot extraction).
// w2t: 129 rows; rows 0..127 real, row 128 zero (sentinel).
// ---------------------------------------------------------------------------
__global__ __launch_bounds__(64) void snn_prep(const float* __restrict__ W1,
                                               const float* __restrict__ W2,
                                               f32x2* __restrict__ w1t,
                                               f32x2* __restrict__ w2t) {
  const int l = threadIdx.x;
  for (int j = 0; j < 64; ++j)
    w1t[j * 64 + l] = (j < 32) ? f32x2{W1[l * 32 + j], W1[(64 + l) * 32 + j]}
                               : f32x2{0.f, 0.f};
  for (int j = 0; j < 129; ++j)
    w2t[j * 64 + l] = (j < 128) ? f32x2{W2[l * 128 + j], W2[(64 + l) * 128 + j]}
                                : f32x2{0.f, 0.f};
}

// ---------------------------------------------------------------------------
// Kernel 1: delta encode -> 32-bit masks (verbatim from passing rounds 4/5).
// ---------------------------------------------------------------------------
__global__ __launch_bounds__(64) void snn_encode(const float* __restrict__ x,
                                                 uint32_t* __restrict__ masks) {
  __shared__ float tile[2][4][64][16];  // 32 KiB
  const int lane = threadIdx.x;
  const int sub = lane >> 4;
  const int f = lane & 15;
  const int b0 = blockIdx.x * 4;
  float ref = x[(size_t)(b0 + sub) * (TT * FDIM) + f];

  const float4* xv = (const float4*)x;
  float4 ld[16];
#define K1_ISSUE(G)                                                           \
  _Pragma("unroll") for (int k = 0; k < 16; ++k) {                            \
    int idx4 = k * 64 + lane;                                                 \
    int bl = idx4 >> 8;                                                       \
    int r = idx4 & 255;                                                       \
    ld[k] = xv[(size_t)(b0 + bl) * (TT * 4) + (size_t)(G) * 256 + r];         \
  }
#define K1_WRITE(BUF)                                                         \
  _Pragma("unroll") for (int k = 0; k < 16; ++k) {                            \
    int idx4 = k * 64 + lane;                                                 \
    int bl = idx4 >> 8;                                                       \
    int r = idx4 & 255;                                                       \
    ((float4*)&tile[BUF][bl][0][0])[r] = ld[k];                               \
  }
#define CHUNK_ISSUE(ARR, A)                                                   \
  {                                                                           \
    DS_READ_OFF(ARR[0], A, 0);                                                \
    DS_READ_OFF(ARR[1], A, 64);                                               \
    DS_READ_OFF(ARR[2], A, 128);                                              \
    DS_READ_OFF(ARR[3], A, 192);                                              \
    DS_READ_OFF(ARR[4], A, 256);                                              \
    DS_READ_OFF(ARR[5], A, 320);                                              \
    DS_READ_OFF(ARR[6], A, 384);                                              \
    DS_READ_OFF(ARR[7], A, 448);                                              \
  }
#define PROC8(ARR, TBASE)                                                     \
  _Pragma("unroll") for (int i = 0; i < 8; ++i) {                             \
    float cur = ARR[i];                                                       \
    float diff = cur - ref;                                                   \
    bool onb = diff >= 0.5f;                                                  \
    bool offb = diff <= -0.5f;                                                \
    u64 bon = __ballot(onb);                                                  \
    u64 boff = __ballot(offb);                                                \
    ref = (onb || offb) ? cur : ref;                                          \
    if (f == 0) {                                                             \
      uint32_t mk = (uint32_t)((bon >> (sub * 16)) & 0xFFFFull) |             \
                    ((uint32_t)((boff >> (sub * 16)) & 0xFFFFull) << 16);     \
      masks[(size_t)(b0 + sub) * TT + ((TBASE) + i)] = mk;                    \
    }                                                                         \
  }

  const uint32_t tbase =
      lds_addr32(&tile[0][0][0][0]) + (uint32_t)sub * 4096u + (uint32_t)f * 4u;

  K1_ISSUE(0);
  K1_WRITE(0);
  WAIT_LGKM(0);
  for (int g = 0; g < TT / 64; ++g) {
    if (g + 1 < TT / 64) K1_ISSUE(g + 1);
    const int buf = g & 1;
    const uint32_t caddr = tbase + (uint32_t)buf * 16384u;
    float va[8], vb[8];
    CHUNK_ISSUE(va, caddr);
#pragma unroll
    for (int c = 0; c < 8; ++c) {
      if (c < 7) {
        uint32_t an = caddr + (uint32_t)(c + 1) * 512u;
        if (c & 1) {
          CHUNK_ISSUE(va, an);
        } else {
          CHUNK_ISSUE(vb, an);
        }
        WAIT_LGKM(8);
      } else {
        WAIT_LGKM(0);
      }
      if (c & 1) {
        PROC8(vb, g * 64 + c * 8);
      } else {
        PROC8(va, g * 64 + c * 8);
      }
    }
    if (g + 1 < TT / 64) {
      K1_WRITE((g + 1) & 1);
      WAIT_LGKM(0);
    }
  }
#undef PROC8
#undef CHUNK_ISSUE
#undef K1_WRITE
#undef K1_ISSUE
}

// ---------------------------------------------------------------------------
// Kernel 2: producer/consumer SNN core. One block (8 waves, 512 thr) per
// batch. Chunk-synchronous pipeline, one __syncthreads per iteration, all
// cross-wave LDS buffers parity-double-buffered (every read's data was
// written >=1 barrier earlier):
//   iter k: producers write C1(k), C2(k-2), C3(k-4);
//           consumer scans chunk k-1 (LIF1->spk1), k-3 (LIF2->spk2),
//           k-5 (LIF3->out).
// ---------------------------------------------------------------------------
__global__ __launch_bounds__(NTHR, 1) void snn_core6(
    const uint32_t* __restrict__ masks, const f32x2* __restrict__ w1t,
    const f32x2* __restrict__ w2t, const float* __restrict__ b1,
    const float* __restrict__ b2, const float* __restrict__ W3,
    const float* __restrict__ b3, float* __restrict__ out) {
  __shared__ __align__(16) uint32_t mks[TT];   // 16 KB input masks
  __shared__ f32x2 C1b[2][CH][64];             // 32 KB
  __shared__ f32x2 C2b[2][CH][64];             // 32 KB
  __shared__ f32x2 C3b[2][CH];                 // 512 B
  __shared__ __align__(16) u64 S1[2][CH][2];   // 1 KB spk1 ballots
  __shared__ __align__(16) u64 S2[2][CH][2];   // 1 KB spk2 ballots

  const int tid = threadIdx.x;
  const int lane = tid & 63;
  const int wv = tid >> 6;
  const int b = blockIdx.x;
  const uint32_t lane8 = (uint32_t)lane * 8u;

  {  // stage this batch's masks into LDS (coalesced)
    const u32x4* src = (const u32x4*)(masks + (size_t)b * TT);
    u32x4* dst = (u32x4*)mks;
    for (int i = tid; i < TT / 4; i += NTHR) dst[i] = src[i];
  }
  const f32x2 bias1 = {b1[lane], b1[64 + lane]};
  const f32x2 bias2 = {b2[lane], b2[64 + lane]};
  const float w30a = W3[lane], w30b = W3[64 + lane];
  const float w31a = W3[128 + lane], w31b = W3[192 + lane];
  const float b30 = b3[0], b31 = b3[1];
  float m1a = 0.f, m1b = 0.f, m2a = 0.f, m2b = 0.f, m3x = 0.f, m3y = 0.f;
  float2* outv = (float2*)out;
  __syncthreads();

// ---- producer task helpers (vm ledger: exactly 24 volatile loads/task) ----
#define EXTRACT(J)                                                            \
  {                                                                           \
    bool av_ = (a_ != 0);                                                     \
    bool bv_ = (b_ != 0);                                                     \
    uint32_t ja_ = av_ ? (uint32_t)__builtin_ctzll(a_) : 0u;                  \
    uint32_t jb_ = bv_ ? 64u + (uint32_t)__builtin_ctzll(b_) : 128u;          \
    J = av_ ? ja_ : jb_;                                                      \
    u64 an_ = a_ & (a_ - 1);                                                  \
    u64 bn_ = b_ & (b_ - 1);                                                  \
    b_ = (!av_ && bv_) ? bn_ : b_;                                            \
    a_ = av_ ? an_ : a_;                                                      \
  }
#define P_ISSUE(TASK, BUF, RA, RB)                                            \
  {                                                                           \
    if ((TASK) < CH) { /* C1 task, chunk k */                                 \
      uint32_t mk_ = (k < NCH) ? mks[k * CH + (TASK)] : 0u;                   \
      mk_ = (uint32_t)__builtin_amdgcn_readfirstlane((int)mk_);               \
      u64 mm_ = (u64)mk_ | 0x00FFFFFF00000000ull; /* 24 guard bits 32..55 */  \
      _Pragma("unroll") for (int s = 0; s < 24; ++s) {                        \
        uint32_t j_ = (uint32_t)__builtin_ctzll(mm_);                         \
        mm_ &= mm_ - 1;                                                       \
        BUF[s] = glb_load_b64((j_ << 9) + lane8, w1t);                        \
      }                                                                       \
      RA = 0;                                                                 \
      RB = 0;                                                                 \
    } else { /* C2 task, chunk k-2 */                                         \
      int c2_ = k - 2;                                                        \
      bool ok_ = (c2_ >= 0) && (c2_ < NCH);                                   \
      u64 a_ = ok_ ? S1[c2_ & 1][(TASK) - CH][0] : 0ull;                      \
      u64 b_ = ok_ ? S1[c2_ & 1][(TASK) - CH][1] : 0ull;                      \
      a_ = rfl64(a_);                                                         \
      b_ = rfl64(b_);                                                         \
      _Pragma("unroll") for (int s = 0; s < 24; ++s) {                        \
        uint32_t j_;                                                          \
        EXTRACT(j_);                                                          \
        BUF[s] = glb_load_b64((j_ << 9) + lane8, w2t);                        \
      }                                                                       \
      RA = a_;                                                                \
      RB = b_;                                                                \
    }                                                                         \
  }
#define P_CONSUME(TASK, BUF, RA, RB)                                          \
  {                                                                           \
    f32x2 c_ = {0.f, 0.f};                                                    \
    _Pragma("unroll") for (int s = 0; s < 24; ++s) c_ = pk_add(c_, BUF[s]);   \
    if ((TASK) < CH) {                                                        \
      if (k < NCH) {                                                          \
        c_ = pk_add(c_, bias1);                                               \
        C1b[k & 1][(TASK)][lane] = c_;                                        \
      }                                                                       \
    } else {                                                                  \
      int c2_ = k - 2;                                                        \
      if (c2_ >= 0 && c2_ < NCH) {                                            \
        u64 ta_ = RA;  /* rare >24-spike tails: exact A-then-B order */       \
        while (ta_) {                                                         \
          uint32_t j_ = (uint32_t)__builtin_ctzll(ta_);                       \
          ta_ &= ta_ - 1;                                                     \
          f32x2 tw_ = glb_load_b64((j_ << 9) + lane8, w2t);                   \
          WAIT_VM(0);                                                         \
          c_ = pk_add(c_, tw_);                                               \
        }                                                                     \
        u64 tb_ = RB;                                                         \
        while (tb_) {                                                         \
          uint32_t j_ = 64u + (uint32_t)__builtin_ctzll(tb_);                 \
          tb_ &= tb_ - 1;                                                     \
          f32x2 tw_ = glb_load_b64((j_ << 9) + lane8, w2t);                   \
          WAIT_VM(0);                                                         \
          c_ = pk_add(c_, tw_);                                               \
        }                                                                     \
        c_ = pk_add(c_, bias2);                                               \
        C2b[c2_ & 1][(TASK) - CH][lane] = c_;                                 \
      }                                                                       \
    }                                                                         \
  }
#define C3_TASK(T3)                                                           \
  {                                                                           \
    int c3_ = k - 4;                                                          \
    if (c3_ >= 0 && c3_ < NCH) {                                              \
      u64 a_ = rfl64(S2[c3_ & 1][(T3)][0]);                                   \
      u64 b_ = rfl64(S2[c3_ & 1][(T3)][1]);                                   \
      float v0 = (((a_ >> lane) & 1) ? w30a : 0.f) +                          \
                 (((b_ >> lane) & 1) ? w30b : 0.f);                           \
      float v1 = (((a_ >> lane) & 1) ? w31a : 0.f) +                          \
                 (((b_ >> lane) & 1) ? w31b : 0.f);                           \
      float r0 = wave_red_add63(v0);                                          \
      float r1 = wave_red_add63(v1);                                          \
      if (lane == 63) C3b[c3_ & 1][(T3)] = f32x2{r0 + b30, r1 + b31};         \
    }                                                                         \
  }

// ---- consumer helpers (lgkm ledger: asm ds reads + batched asm writes) ----
#define ISSUE8_512(ARR, A)                                                    \
  {                                                                           \
    DSR64(ARR[0], A, 0);                                                      \
    DSR64(ARR[1], A, 512);                                                    \
    DSR64(ARR[2], A, 1024);                                                   \
    DSR64(ARR[3], A, 1536);                                                   \
    DSR64(ARR[4], A, 2048);                                                   \
    DSR64(ARR[5], A, 2560);                                                   \
    DSR64(ARR[6], A, 3072);                                                   \
    DSR64(ARR[7], A, 3584);                                                   \
  }
#define ISSUE8_S8(ARR, A)                                                     \
  {                                                                           \
    DSR64(ARR[0], A, 0);                                                      \
    DSR64(ARR[1], A, 8);                                                      \
    DSR64(ARR[2], A, 16);                                                     \
    DSR64(ARR[3], A, 24);                                                     \
    DSR64(ARR[4], A, 32);                                                     \
    DSR64(ARR[5], A, 40);                                                     \
    DSR64(ARR[6], A, 48);                                                     \
    DSR64(ARR[7], A, 56);                                                     \
  }
#define SSTEP(ARR, I, NW, PKA, MA, MB)                                        \
  {                                                                           \
    WAIT_LGKM(NW);                                                            \
    f32x2 cv_ = ARR[I];                                                       \
    float n0_ = __fadd_rn(__fmul_rn(0.9f, MA), cv_.x);                        \
    float n1_ = __fadd_rn(__fmul_rn(0.9f, MB), cv_.y);                        \
    MA = (MA > 1.f) ? (n0_ - 1.f) : n0_;                                      \
    MB = (MB > 1.f) ? (n1_ - 1.f) : n1_;                                      \
    u64 s0_ = __ballot(MA > 1.f);                                             \
    u64 s1_ = __ballot(MB > 1.f);                                             \
    PKA[I] = u32x4{(uint32_t)s0_, (uint32_t)(s0_ >> 32), (uint32_t)s1_,       \
                   (uint32_t)(s1_ >> 32)};                                    \
  }
#define SGRP_DESC(ARR, PKA, MA, MB)                                           \
  SSTEP(ARR, 0, 15, PKA, MA, MB)                                              \
  SSTEP(ARR, 1, 14, PKA, MA, MB)                                              \
  SSTEP(ARR, 2, 13, PKA, MA, MB)                                              \
  SSTEP(ARR, 3, 12, PKA, MA, MB)                                              \
  SSTEP(ARR, 4, 11, PKA, MA, MB)                                              \
  SSTEP(ARR, 5, 10, PKA, MA, MB)                                              \
  SSTEP(ARR, 6, 9, PKA, MA, MB)                                               \
  SSTEP(ARR, 7, 8, PKA, MA, MB)
#define SGRP_15(ARR, PKA, MA, MB)                                             \
  SSTEP(ARR, 0, 15, PKA, MA, MB)                                              \
  SSTEP(ARR, 1, 15, PKA, MA, MB)                                              \
  SSTEP(ARR, 2, 15, PKA, MA, MB)                                              \
  SSTEP(ARR, 3, 15, PKA, MA, MB)                                              \
  SSTEP(ARR, 4, 15, PKA, MA, MB)                                              \
  SSTEP(ARR, 5, 15, PKA, MA, MB)                                              \
  SSTEP(ARR, 6, 15, PKA, MA, MB)                                              \
  SSTEP(ARR, 7, 15, PKA, MA, MB)
#define SPK_WRITE8(PKA, SB, TOFF)                                             \
  if (lane == 0) {                                                            \
    _Pragma("unroll") for (int i = 0; i < 8; ++i)                             \
        ds_write_b128_at((SB) + (uint32_t)(((TOFF) + i) * 16), PKA[i]);       \
  }
#define SCAN12(CHK, CBUF, SBUF, MA, MB)                                       \
  {                                                                           \
    const int par_ = (CHK) & 1;                                               \
    const uint32_t rb_ = lds_addr32(&CBUF[par_][0][0]) + lane8;               \
    const uint32_t sb_ = lds_addr32(&SBUF[par_][0][0]);                       \
    f32x2 va_[8], vb_[8];                                                     \
    u32x4 pk_[8];                                                             \
    ISSUE8_512(va_, rb_);                                                     \
    const uint32_t rb1_ = rb_ + 4096u;                                        \
    ISSUE8_512(vb_, rb1_);                                                    \
    SGRP_DESC(va_, pk_, MA, MB)                                               \
    SPK_WRITE8(pk_, sb_, 0);                                                  \
    const uint32_t rb2_ = rb_ + 8192u;                                        \
    ISSUE8_512(va_, rb2_);                                                    \
    SGRP_15(vb_, pk_, MA, MB)                                                 \
    SPK_WRITE8(pk_, sb_, 8);                                                  \
    const uint32_t rb3_ = rb_ + 12288u;                                       \
    ISSUE8_512(vb_, rb3_);                                                    \
    SGRP_15(va_, pk_, MA, MB)                                                 \
    SPK_WRITE8(pk_, sb_, 16);                                                 \
    SGRP_DESC(vb_, pk_, MA, MB)                                               \
    SPK_WRIT8_DUMMY                                                           \
    SPK_WRITE8(pk_, sb_, 24);                                                 \
  }
#define SPK_WRIT8_DUMMY
#define SPK_WRITE8_DUMMY
#define SPK_WRIT8_DUMMY2
#define S3STEP(ARR, I, NW, T_)                                                \
  {                                                                           \
    WAIT_LGKM(NW);                                                            \
    f32x2 c3_ = ARR[I];                                                       \
    float e0_ = __fadd_rn(__fmul_rn(0.9f, m3x), c3_.x);                       \
    float e1_ = __fadd_rn(__fmul_rn(0.9f, m3y), c3_.y);                       \
    m3x = (m3x > 1.f) ? (e0_ - 1.f) : e0_;                                    \
    m3y = (m3y > 1.f) ? (e1_ - 1.f) : e1_;                                    \
    if (lane == 0) outv[(size_t)(T_)*BB + b] = make_float2(m3x, m3y);         \
  }
#define S3GRP_DESC(ARR, TB)                                                   \
  S3STEP(ARR, 0, 15, (TB) + 0)                                                \
  S3STEP(ARR, 1, 14, (TB) + 1)                                                \
  S3STEP(ARR, 2, 13, (TB) + 2)                                                \
  S3STEP(ARR, 3, 12, (TB) + 3)                                                \
  S3STEP(ARR, 4, 11, (TB) + 4)                                                \
  S3STEP(ARR, 5, 10, (TB) + 5)                                                \
  S3STEP(ARR, 6, 9, (TB) + 6)                                                 \
  S3STEP(ARR, 7, 8, (TB) + 7)
#define S3GRP_TAIL(ARR, TB)                                                   \
  S3STEP(ARR, 0, 7, (TB) + 0)                                                 \
  S3STEP(ARR, 1, 6, (TB) + 1)                                                 \
  S3STEP(ARR, 2, 5, (TB) + 2)                                                 \
  S3STEP(ARR, 3, 4, (TB) + 3)                                                 \
  S3STEP(ARR, 4, 3, (TB) + 4)                                                 \
  S3STEP(ARR, 5, 2, (TB) + 5)                                                 \
  S3STEP(ARR, 6, 1, (TB) + 6)                                                 \
  S3STEP(ARR, 7, 0, (TB) + 7)
#define SCAN3K(CHK)                                                           \
  {                                                                           \
    const int par_ = (CHK) & 1;                                               \
    const uint32_t cb_ = lds_addr32(&C3b[par_][0]);                           \
    f32x2 vc_[8], vd_[8];                                                     \
    ISSUE8_S8(vc_, cb_);                                                      \
    const uint32_t cb1_ = cb_ + 64u;                                          \
    ISSUE8_S8(vd_, cb1_);                                                     \
    S3GRP_DESC(vc_, (CHK)*CH + 0)                                             \
    const uint32_t cb2_ = cb_ + 128u;                                         \
    ISSUE8_S8(vc_, cb2_);                                                     \
    S3GRP_DESC(vd_, (CHK)*CH + 8)                                             \
    const uint32_t cb3_ = cb_ + 192u;                                         \
    ISSUE8_S8(vd_, cb3_);                                                     \
    S3GRP_DESC(vc_, (CHK)*CH + 16)                                            \
    S3GRP_TAIL(vd_, (CHK)*CH + 24)                                            \
  }

  // ================= chunk-synchronous main pipeline =================
  for (int k = 0; k < NCH + 5; ++k) {
    __syncthreads();
    if (wv < NPROD) {
      // vm tasks: ids 0..31 = C1(chunk k), 32..63 = C2(chunk k-2).
      // 2-deep ping-pong pipeline, exact vmcnt(24) ledger.
      f32x2 P[24], Q[24];
      u64 raP = 0, rbP = 0, raQ = 0, rbQ = 0;
      int ti = wv;
      P_ISSUE(ti, P, raP, rbP);
      for (;;) {
        int tn = ti + NPROD;
        if (tn < 64) {
          P_ISSUE(tn, Q, raQ, rbQ);
          WAIT_VM(24);
        } else {
          WAIT_VM(0);
        }
        P_CONSUME(ti, P, raP, rbP);
        if (tn >= 64) break;
        ti = tn + NPROD;
        if (ti < 64) {
          P_ISSUE(ti, P, raP, rbP);
          WAIT_VM(24);
        } else {
          WAIT_VM(0);
        }
        P_CONSUME(tn, Q, raQ, rbQ);
        if (ti >= 64) break;
      }
      for (int t3 = wv; t3 < CH; t3 += NPROD) {
        C3_TASK(t3);
      }
    } else {
      if (k >= 1 && k - 1 < NCH) SCAN12(k - 1, C1b, S1, m1a, m1b);
      if (k >= 3 && k - 3 < NCH) SCAN12(k - 3, C2b, S2, m2a, m2b);
      if (k >= 5 && k - 5 < NCH) SCAN3K(k - 5);
    }
  }
#undef SCAN3K
#undef S3GRP_TAIL
#undef S3GRP_DESC
#undef S3STEP
#undef SCAN12
#undef SPK_WRITE8
#undef SGRP_15
#undef SGRP_DESC
#undef SSTEP
#undef ISSUE8_S8
#undef ISSUE8_512
#undef C3_TASK
#undef P_CONSUME
#undef P_ISSUE
#undef EXTRACT
}

extern "C" void kernel_launch(void* const* d_in, const int* in_sizes, int n_in,
                              void* d_out, int out_size, void* d_ws,
                              size_t ws_size, hipStream_t stream) {
  const float* x = (const float*)d_in[0];
  const float* W1 = (const float*)d_in[1];
  const float* b1 = (const float*)d_in[2];
  const float* W2 = (const float*)d_in[3];
  const float* b2 = (const float*)d_in[4];
  const float* W3 = (const float*)d_in[5];
  const float* b3 = (const float*)d_in[6];
  float* out = (float*)d_out;

  uint32_t* masks = (uint32_t*)d_ws;                         // 4 MiB
  char* wbase = (char*)d_ws + (size_t)BB * TT * 4;
  f32x2* w1t = (f32x2*)wbase;                                // 32768 B
  f32x2* w2t = (f32x2*)(wbase + 32768);                      // 66048 B

  snn_prep<<<1, 64, 0, stream>>>(W1, W2, w1t, w2t);
  snn_encode<<<BB / 4, 64, 0, stream>>>(x, masks);
  snn_core6<<<BB, NTHR, 0, stream>>>(masks, w1t, w2t, b1, b2, W3, b3, out);
}